// Round 10
// baseline (57.675 us; speedup 1.0000x reference)
//
#include <hip/hip_runtime.h>

#define LOG2E    1.4426950408889634f
#define TWOLOG2E 2.8853900817779268f
#define LDP 130

// ---------------------------------------------------------------------------
// Kernel 1 (fused): per (kt,qt,b) block:
//   - project its 32 q-rows and 32 k-rows (redundantly across blocks; costs
//     ~7us chip-wide but deletes 2 launches + the qp/kp global round-trip)
//   - compute P = exp(score) tile + column partial sums Zpart
// LDS: qs/ks double as x-staging (stride 128) then proj output (stride 130).
// 51.3 KB -> 3 blocks/CU.
// ---------------------------------------------------------------------------
__global__ __launch_bounds__(256) void fusedP_kernel(
    const float* __restrict__ queries, const float* __restrict__ keys,
    const float* __restrict__ Wq, const float* __restrict__ Wk,
    const float* __restrict__ wv, float* __restrict__ P,
    float* __restrict__ Zpart)
{
    __shared__ float qs[32 * LDP];     // xq (stride 128) then q-proj (stride 130)
    __shared__ float ks_[32 * LDP];    // xk then k-proj
    __shared__ float Wc[128 * 33];     // W chunk: 128 h x 32 d, stride 33
    __shared__ float w2s[128];         // -2 * wv
    __shared__ float part2[4][32];

    const int kt = blockIdx.x, qt = blockIdx.y, b = blockIdx.z;
    const int t = threadIdx.x;

    // ---- stage x tiles (coalesced) ----
    {
        const float4* qsrc = (const float4*)(queries + (size_t)(b * 256 + qt * 32) * 128);
        const float4* ksrc = (const float4*)(keys    + (size_t)(b * 256 + kt * 32) * 128);
        #pragma unroll
        for (int j = 0; j < 4; ++j) {
            ((float4*)qs)[t + j * 256]  = qsrc[t + j * 256];
            ((float4*)ks_)[t + j * 256] = ksrc[t + j * 256];
        }
        if (t < 32) {
            float4 w = ((const float4*)wv)[t];
            *(float4*)&w2s[t * 4] = make_float4(-2.f * w.x, -2.f * w.y,
                                                -2.f * w.z, -2.f * w.w);
        }
    }

    // ---- projection: thread owns 4 rows x 4 h outer-product sub-tile ----
    const int r0 = (t >> 5) * 4;       // 0..28
    const int h0 = (t & 31) * 4;       // 0..124
    float acc[4][4];

    // q-side
    #pragma unroll
    for (int i = 0; i < 4; ++i)
        #pragma unroll
        for (int j = 0; j < 4; ++j) acc[i][j] = 0.f;
    for (int c = 0; c < 4; ++c) {
        __syncthreads();               // Wc free (also covers x staging, c=0)
        #pragma unroll
        for (int j = 0; j < 16; ++j) { // stage Wq chunk, coalesced 128B rows
            int i = t + j * 256;       // 0..4095
            Wc[(i >> 5) * 33 + (i & 31)] = Wq[(size_t)(i >> 5) * 128 + c * 32 + (i & 31)];
        }
        __syncthreads();
        #pragma unroll
        for (int d4 = 0; d4 < 8; ++d4) {
            float4 xa0 = *(const float4*)&qs[(r0 + 0) * 128 + c * 32 + d4 * 4];
            float4 xa1 = *(const float4*)&qs[(r0 + 1) * 128 + c * 32 + d4 * 4];
            float4 xa2 = *(const float4*)&qs[(r0 + 2) * 128 + c * 32 + d4 * 4];
            float4 xa3 = *(const float4*)&qs[(r0 + 3) * 128 + c * 32 + d4 * 4];
            #pragma unroll
            for (int j = 0; j < 4; ++j) {
                const float* wr = &Wc[(h0 + j) * 33 + d4 * 4];
                float w0 = wr[0], w1 = wr[1], w2 = wr[2], w3 = wr[3];
                acc[0][j] = fmaf(xa0.x, w0, acc[0][j]); acc[0][j] = fmaf(xa0.y, w1, acc[0][j]);
                acc[0][j] = fmaf(xa0.z, w2, acc[0][j]); acc[0][j] = fmaf(xa0.w, w3, acc[0][j]);
                acc[1][j] = fmaf(xa1.x, w0, acc[1][j]); acc[1][j] = fmaf(xa1.y, w1, acc[1][j]);
                acc[1][j] = fmaf(xa1.z, w2, acc[1][j]); acc[1][j] = fmaf(xa1.w, w3, acc[1][j]);
                acc[2][j] = fmaf(xa2.x, w0, acc[2][j]); acc[2][j] = fmaf(xa2.y, w1, acc[2][j]);
                acc[2][j] = fmaf(xa2.z, w2, acc[2][j]); acc[2][j] = fmaf(xa2.w, w3, acc[2][j]);
                acc[3][j] = fmaf(xa3.x, w0, acc[3][j]); acc[3][j] = fmaf(xa3.y, w1, acc[3][j]);
                acc[3][j] = fmaf(xa3.z, w2, acc[3][j]); acc[3][j] = fmaf(xa3.w, w3, acc[3][j]);
            }
        }
    }
    __syncthreads();                   // all xq reads done
    #pragma unroll
    for (int i = 0; i < 4; ++i)
        #pragma unroll
        for (int j = 0; j < 4; ++j)
            qs[(r0 + i) * LDP + h0 + j] = acc[i][j] * TWOLOG2E;

    // k-side (reuse acc, Wc)
    #pragma unroll
    for (int i = 0; i < 4; ++i)
        #pragma unroll
        for (int j = 0; j < 4; ++j) acc[i][j] = 0.f;
    for (int c = 0; c < 4; ++c) {
        __syncthreads();
        #pragma unroll
        for (int j = 0; j < 16; ++j) {
            int i = t + j * 256;
            Wc[(i >> 5) * 33 + (i & 31)] = Wk[(size_t)(i >> 5) * 128 + c * 32 + (i & 31)];
        }
        __syncthreads();
        #pragma unroll
        for (int d4 = 0; d4 < 8; ++d4) {
            float4 xa0 = *(const float4*)&ks_[(r0 + 0) * 128 + c * 32 + d4 * 4];
            float4 xa1 = *(const float4*)&ks_[(r0 + 1) * 128 + c * 32 + d4 * 4];
            float4 xa2 = *(const float4*)&ks_[(r0 + 2) * 128 + c * 32 + d4 * 4];
            float4 xa3 = *(const float4*)&ks_[(r0 + 3) * 128 + c * 32 + d4 * 4];
            #pragma unroll
            for (int j = 0; j < 4; ++j) {
                const float* wr = &Wc[(h0 + j) * 33 + d4 * 4];
                float w0 = wr[0], w1 = wr[1], w2 = wr[2], w3 = wr[3];
                acc[0][j] = fmaf(xa0.x, w0, acc[0][j]); acc[0][j] = fmaf(xa0.y, w1, acc[0][j]);
                acc[0][j] = fmaf(xa0.z, w2, acc[0][j]); acc[0][j] = fmaf(xa0.w, w3, acc[0][j]);
                acc[1][j] = fmaf(xa1.x, w0, acc[1][j]); acc[1][j] = fmaf(xa1.y, w1, acc[1][j]);
                acc[1][j] = fmaf(xa1.z, w2, acc[1][j]); acc[1][j] = fmaf(xa1.w, w3, acc[1][j]);
                acc[2][j] = fmaf(xa2.x, w0, acc[2][j]); acc[2][j] = fmaf(xa2.y, w1, acc[2][j]);
                acc[2][j] = fmaf(xa2.z, w2, acc[2][j]); acc[2][j] = fmaf(xa2.w, w3, acc[2][j]);
                acc[3][j] = fmaf(xa3.x, w0, acc[3][j]); acc[3][j] = fmaf(xa3.y, w1, acc[3][j]);
                acc[3][j] = fmaf(xa3.z, w2, acc[3][j]); acc[3][j] = fmaf(xa3.w, w3, acc[3][j]);
            }
        }
    }
    __syncthreads();                   // all xk reads done
    #pragma unroll
    for (int i = 0; i < 4; ++i)
        #pragma unroll
        for (int j = 0; j < 4; ++j)
            ks_[(r0 + i) * LDP + h0 + j] = acc[i][j] * TWOLOG2E;
    __syncthreads();                   // proj tiles ready

    // ---- scoreP body (identical math to R3) ----
    float wsum = 0.f;
    #pragma unroll 8
    for (int i = 0; i < 32; ++i) {
        float4 w = *(const float4*)&w2s[i * 4];
        wsum += (w.x + w.y) + (w.z + w.w);
    }
    wsum *= -0.5f;

    const int lk = (t & 15) * 2;
    const int lq = (t >> 4) * 2;

    float a00 = 0.f, a01 = 0.f, a10 = 0.f, a11 = 0.f;

    #pragma unroll 4
    for (int h = 0; h < 128; h += 4) {
        float4 w4 = *(const float4*)&w2s[h];
        float4 qa = *(const float4*)&qs[lq * LDP + h];
        float4 qb = *(const float4*)&qs[(lq + 1) * LDP + h];
        float4 ka = *(const float4*)&ks_[lk * LDP + h];
        float4 kb = *(const float4*)&ks_[(lk + 1) * LDP + h];
        const float wj[4]  = {w4.x, w4.y, w4.z, w4.w};
        const float qaj[4] = {qa.x, qa.y, qa.z, qa.w};
        const float qbj[4] = {qb.x, qb.y, qb.z, qb.w};
        const float kaj[4] = {ka.x, ka.y, ka.z, ka.w};
        const float kbj[4] = {kb.x, kb.y, kb.z, kb.w};
        #pragma unroll
        for (int j = 0; j < 4; ++j) {
            float r00 = __builtin_amdgcn_rcpf(__builtin_amdgcn_exp2f(qaj[j] + kaj[j]) + 1.0f);
            float r01 = __builtin_amdgcn_rcpf(__builtin_amdgcn_exp2f(qaj[j] + kbj[j]) + 1.0f);
            float r10 = __builtin_amdgcn_rcpf(__builtin_amdgcn_exp2f(qbj[j] + kaj[j]) + 1.0f);
            float r11 = __builtin_amdgcn_rcpf(__builtin_amdgcn_exp2f(qbj[j] + kbj[j]) + 1.0f);
            a00 = fmaf(wj[j], r00, a00);
            a01 = fmaf(wj[j], r01, a01);
            a10 = fmaf(wj[j], r10, a10);
            a11 = fmaf(wj[j], r11, a11);
        }
    }

    float p00 = __builtin_amdgcn_exp2f((a00 + wsum) * LOG2E);
    float p01 = __builtin_amdgcn_exp2f((a01 + wsum) * LOG2E);
    float p10 = __builtin_amdgcn_exp2f((a10 + wsum) * LOG2E);
    float p11 = __builtin_amdgcn_exp2f((a11 + wsum) * LOG2E);

    const int q = qt * 32 + lq;
    const int k = kt * 32 + lk;
    *(float2*)&P[((size_t)(b * 256 + q)) * 256 + k]     = make_float2(p00, p01);
    *(float2*)&P[((size_t)(b * 256 + q + 1)) * 256 + k] = make_float2(p10, p11);

    float sa = p00 + p10;
    float sb = p01 + p11;
    sa += __shfl_xor(sa, 16, 64);
    sa += __shfl_xor(sa, 32, 64);
    sb += __shfl_xor(sb, 16, 64);
    sb += __shfl_xor(sb, 32, 64);
    const int wid = t >> 6;
    if ((t & 63) < 16) {
        part2[wid][lk]     = sa;
        part2[wid][lk + 1] = sb;
    }
    __syncthreads();
    if (t < 32) {
        float z = part2[0][t] + part2[1][t] + part2[2][t] + part2[3][t];
        Zpart[(size_t)b * 2048 + qt * 256 + kt * 32 + t] = z;
    }
}

// ---------------------------------------------------------------------------
// Kernel 2: out[b][q][d] = sum_k P[b,q,k]*c[b,k]*v[b,k,d], c = 1/sum Zpart.
// (verbatim from R9) grid 512 blocks, 256 threads; waves split k, LDS combine.
// ---------------------------------------------------------------------------
__global__ __launch_bounds__(256) void pv_kernel(
    const float* __restrict__ P, const float* __restrict__ Zpart,
    const float* __restrict__ values, float* __restrict__ out)
{
    __shared__ float ps[4 * 260];
    __shared__ float red[4 * 512];
    const int b  = blockIdx.x >> 6;
    const int q0 = (blockIdx.x & 63) * 4;
    const int t  = threadIdx.x;

    {
        const int q = t >> 6;
        const int k = (t & 63) * 4;
        const float* zb = Zpart + (size_t)b * 2048 + k;
        float4 z = make_float4(0.f, 0.f, 0.f, 0.f);
        #pragma unroll
        for (int qt = 0; qt < 8; ++qt) {
            float4 a = *(const float4*)(zb + qt * 256);
            z.x += a.x; z.y += a.y; z.z += a.z; z.w += a.w;
        }
        const float* prow = P + ((size_t)(b * 256 + q0 + q)) * 256 + k;
        float4 s = *(const float4*)prow;
        float4 r;
        r.x = s.x * __builtin_amdgcn_rcpf(z.x);
        r.y = s.y * __builtin_amdgcn_rcpf(z.y);
        r.z = s.z * __builtin_amdgcn_rcpf(z.z);
        r.w = s.w * __builtin_amdgcn_rcpf(z.w);
        *(float4*)&ps[q * 260 + k] = r;
    }
    __syncthreads();

    const int wid  = t >> 6;
    const int lane = t & 63;
    const float* vb = values + (size_t)b * 256 * 128 + lane * 2;

    float ax[4] = {0.f, 0.f, 0.f, 0.f};
    float ay[4] = {0.f, 0.f, 0.f, 0.f};

    for (int kk4 = wid * 16; kk4 < wid * 16 + 16; ++kk4) {
        float4 p0 = *(const float4*)&ps[0 * 260 + kk4 * 4];
        float4 p1 = *(const float4*)&ps[1 * 260 + kk4 * 4];
        float4 p2 = *(const float4*)&ps[2 * 260 + kk4 * 4];
        float4 p3 = *(const float4*)&ps[3 * 260 + kk4 * 4];
        #pragma unroll
        for (int u = 0; u < 4; ++u) {
            int kk = kk4 * 4 + u;
            float2 v = *(const float2*)(vb + (size_t)kk * 128);
            float f0 = (&p0.x)[u], f1 = (&p1.x)[u], f2 = (&p2.x)[u], f3 = (&p3.x)[u];
            ax[0] = fmaf(f0, v.x, ax[0]); ay[0] = fmaf(f0, v.y, ay[0]);
            ax[1] = fmaf(f1, v.x, ax[1]); ay[1] = fmaf(f1, v.y, ay[1]);
            ax[2] = fmaf(f2, v.x, ax[2]); ay[2] = fmaf(f2, v.y, ay[2]);
            ax[3] = fmaf(f3, v.x, ax[3]); ay[3] = fmaf(f3, v.y, ay[3]);
        }
    }

    #pragma unroll
    for (int q = 0; q < 4; ++q)
        *(float2*)&red[wid * 512 + q * 128 + lane * 2] = make_float2(ax[q], ay[q]);
    __syncthreads();

    {
        const int j = t * 2;
        float2 s = make_float2(0.f, 0.f);
        #pragma unroll
        for (int w = 0; w < 4; ++w) {
            float2 r = *(const float2*)&red[w * 512 + j];
            s.x += r.x; s.y += r.y;
        }
        const int q = j >> 7, d = j & 127;
        *(float2*)&out[((size_t)(b * 256 + q0 + q)) * 128 + d] = s;
    }
}

// ---------------------------------------------------------------------------
extern "C" void kernel_launch(void* const* d_in, const int* in_sizes, int n_in,
                              void* d_out, int out_size, void* d_ws, size_t ws_size,
                              hipStream_t stream)
{
    const float* queries = (const float*)d_in[0];  // (8,256,128)
    const float* keys    = (const float*)d_in[1];  // (8,256,128)
    const float* values  = (const float*)d_in[2];  // (8,256,128)
    const float* Wq      = (const float*)d_in[3];  // (128,128)
    const float* Wk      = (const float*)d_in[4];  // (128,128)
    const float* wv      = (const float*)d_in[5];  // (128,)
    float* out = (float*)d_out;                    // (8,256,128)

    float* ws = (float*)d_ws;
    float* P     = ws;                   // 524288 floats  exp(s)
    float* Zpart = ws + 524288;          // 16384 floats

    fusedP_kernel<<<dim3(8, 8, 8), 256, 0, stream>>>(queries, keys, Wq, Wk, wv,
                                                     P, Zpart);
    pv_kernel<<<512, 256, 0, stream>>>(P, Zpart, values, out);
}

// Round 11
// 34.545 us; speedup vs baseline: 1.6696x; 1.6696x over previous
//
#include <hip/hip_runtime.h>

#define LOG2E    1.4426950408889634f
#define TWOLOG2E 2.8853900817779268f

// ---------------------------------------------------------------------------
// Kernel 0: transpose Wq, Wk (128x128) -> WqT, WkT (verbatim R9).
// ---------------------------------------------------------------------------
__global__ __launch_bounds__(256) void transposeW_kernel(
    const float* __restrict__ Wq, const float* __restrict__ Wk,
    float* __restrict__ WqT, float* __restrict__ WkT)
{
    __shared__ float tile[32][33];
    const int m   = blockIdx.x >> 4;            // 0: Wq, 1: Wk
    const int tid = blockIdx.x & 15;            // 4x4 tiles of 32x32
    const int r0 = (tid >> 2) * 32, c0 = (tid & 3) * 32;
    const float* __restrict__ W  = m ? Wk  : Wq;
    float* __restrict__       WT = m ? WkT : WqT;
    const int t = threadIdx.x;

    {
        int r = t >> 3, c4 = (t & 7) * 4;
        float4 v = *(const float4*)(W + (size_t)(r0 + r) * 128 + c0 + c4);
        tile[r][c4 + 0] = v.x; tile[r][c4 + 1] = v.y;
        tile[r][c4 + 2] = v.z; tile[r][c4 + 3] = v.w;
    }
    __syncthreads();
    {
        int c = t >> 3, r4 = (t & 7) * 4;
        float4 v = make_float4(tile[r4 + 0][c], tile[r4 + 1][c],
                               tile[r4 + 2][c], tile[r4 + 3][c]);
        *(float4*)(WT + (size_t)(c0 + c) * 128 + r0 + r4) = v;
    }
}

// ---------------------------------------------------------------------------
// Kernel 1: projections -> EXPONENTIALS.  eq = exp(2 * queries @ Wq^T),
// ek = exp(2 * keys @ Wk^T).  Emitting e^{2x} here lets the score kernel
// form e^{2(q+k)} = eq*ek with a MUL instead of an exp2 per element
// (halves the transcendental count of the dominant kernel).
// grid 512 (256 q + 256 k blocks), 256 threads, 8 rows/block. (R9 skeleton)
// ---------------------------------------------------------------------------
__global__ __launch_bounds__(256) void proj_kernel(
    const float* __restrict__ queries, const float* __restrict__ keys,
    const float* __restrict__ WqT, const float* __restrict__ WkT,
    float* __restrict__ eq, float* __restrict__ ek)
{
    __shared__ float xs[8 * 128];    // 4 KB
    const int isK = blockIdx.x >= 256;
    const int rowBase = (blockIdx.x & 255) * 8;
    const float* __restrict__ x  = isK ? keys : queries;
    const float* __restrict__ WT = isK ? WkT : WqT;
    float* __restrict__ op = isK ? ek : eq;
    const int t = threadIdx.x;

    ((float4*)xs)[t] = ((const float4*)(x + (size_t)rowBase * 128))[t];
    __syncthreads();

    const int h  = t & 127;          // output hidden index (lane -> coalesced)
    const int rh = t >> 7;           // 0: rows 0-3, 1: rows 4-7
    float acc[4] = {0.f, 0.f, 0.f, 0.f};

    #pragma unroll 4
    for (int d4 = 0; d4 < 32; ++d4) {
        float w0 = WT[(size_t)(d4 * 4 + 0) * 128 + h];
        float w1 = WT[(size_t)(d4 * 4 + 1) * 128 + h];
        float w2 = WT[(size_t)(d4 * 4 + 2) * 128 + h];
        float w3 = WT[(size_t)(d4 * 4 + 3) * 128 + h];
        #pragma unroll
        for (int r = 0; r < 4; ++r) {
            float4 xv = *(const float4*)&xs[(rh * 4 + r) * 128 + d4 * 4];
            acc[r] = fmaf(xv.x, w0, acc[r]);
            acc[r] = fmaf(xv.y, w1, acc[r]);
            acc[r] = fmaf(xv.z, w2, acc[r]);
            acc[r] = fmaf(xv.w, w3, acc[r]);
        }
    }
    #pragma unroll
    for (int r = 0; r < 4; ++r)      // coalesced dword stores: e^{2*proj}
        op[(size_t)(rowBase + rh * 4 + r) * 128 + h] =
            __builtin_amdgcn_exp2f(acc[r] * TWOLOG2E);
}

// ---------------------------------------------------------------------------
// Kernel 2: P[b][q][k] = exp(score), score = wsum - 2*sum_h wv[h]*rcp(eq*ek+1)
// (tanh(x) = 1 - 2/(e^{2x}+1), e^{2x} = eq*ek).  wv is read via uniform
// scalar loads (SGPR) -> no LDS staging for it, 4 instead of 5 ds_read_b128
// per h-iter.  Also emits column partial sums Zpart[b][qt][k].
// grid (8,8,8) = 512 blocks, 256 threads, 2q x 2k per thread.
// ---------------------------------------------------------------------------
#define LDP 130

__global__ __launch_bounds__(256) void scoreP_kernel(
    const float* __restrict__ eq, const float* __restrict__ ek,
    const float* __restrict__ wv, float* __restrict__ P,
    float* __restrict__ Zpart)
{
    __shared__ float qs[32 * LDP];
    __shared__ float ks_[32 * LDP];
    __shared__ float part2[4][32];      // per-wave column partials

    const int kt = blockIdx.x, qt = blockIdx.y, b = blockIdx.z;
    const int t = threadIdx.x;

    const float4* qsrc = (const float4*)(eq + (size_t)(b * 256 + qt * 32) * 128);
    const float4* ksrc = (const float4*)(ek + (size_t)(b * 256 + kt * 32) * 128);
    {
        int r = t >> 3, c = (t & 7) * 16;
        #pragma unroll
        for (int j = 0; j < 4; ++j) {
            float4 v  = qsrc[t * 4 + j];
            *(float4*)&qs[r * LDP + c + j * 4] = v;
            float4 v2 = ksrc[t * 4 + j];
            *(float4*)&ks_[r * LDP + c + j * 4] = v2;
        }
    }
    __syncthreads();

    const int lk = (t & 15) * 2;
    const int lq = (t >> 4) * 2;

    float a00 = 0.f, a01 = 0.f, a10 = 0.f, a11 = 0.f;
    float wsum = 0.f;

    #pragma unroll 4
    for (int h = 0; h < 128; h += 4) {
        float4 w4 = *(const float4*)&wv[h];          // uniform -> s_load
        wsum += (w4.x + w4.y) + (w4.z + w4.w);
        float4 qa = *(const float4*)&qs[lq * LDP + h];
        float4 qb = *(const float4*)&qs[(lq + 1) * LDP + h];
        float4 ka = *(const float4*)&ks_[lk * LDP + h];
        float4 kb = *(const float4*)&ks_[(lk + 1) * LDP + h];
        const float wj[4]  = {w4.x, w4.y, w4.z, w4.w};
        const float qaj[4] = {qa.x, qa.y, qa.z, qa.w};
        const float qbj[4] = {qb.x, qb.y, qb.z, qb.w};
        const float kaj[4] = {ka.x, ka.y, ka.z, ka.w};
        const float kbj[4] = {kb.x, kb.y, kb.z, kb.w};
        #pragma unroll
        for (int j = 0; j < 4; ++j) {
            float r00 = __builtin_amdgcn_rcpf(fmaf(qaj[j], kaj[j], 1.0f));
            float r01 = __builtin_amdgcn_rcpf(fmaf(qaj[j], kbj[j], 1.0f));
            float r10 = __builtin_amdgcn_rcpf(fmaf(qbj[j], kaj[j], 1.0f));
            float r11 = __builtin_amdgcn_rcpf(fmaf(qbj[j], kbj[j], 1.0f));
            a00 = fmaf(wj[j], r00, a00);
            a01 = fmaf(wj[j], r01, a01);
            a10 = fmaf(wj[j], r10, a10);
            a11 = fmaf(wj[j], r11, a11);
        }
    }

    // p = exp(wsum - 2*a) = exp2(fma(-2*log2e, a, wsum*log2e))
    const float wsl = wsum * LOG2E;
    const float M2L = -2.0f * LOG2E;
    float p00 = __builtin_amdgcn_exp2f(fmaf(M2L, a00, wsl));
    float p01 = __builtin_amdgcn_exp2f(fmaf(M2L, a01, wsl));
    float p10 = __builtin_amdgcn_exp2f(fmaf(M2L, a10, wsl));
    float p11 = __builtin_amdgcn_exp2f(fmaf(M2L, a11, wsl));

    const int q = qt * 32 + lq;
    const int k = kt * 32 + lk;
    *(float2*)&P[((size_t)(b * 256 + q)) * 256 + k]     = make_float2(p00, p01);
    *(float2*)&P[((size_t)(b * 256 + q + 1)) * 256 + k] = make_float2(p10, p11);

    // column partial sums over this tile's 32 q rows
    float sa = p00 + p10;
    float sb = p01 + p11;
    sa += __shfl_xor(sa, 16, 64);
    sa += __shfl_xor(sa, 32, 64);
    sb += __shfl_xor(sb, 16, 64);
    sb += __shfl_xor(sb, 32, 64);
    const int wid = t >> 6;
    if ((t & 63) < 16) {
        part2[wid][lk]     = sa;
        part2[wid][lk + 1] = sb;
    }
    __syncthreads();
    if (t < 32) {
        float z = part2[0][t] + part2[1][t] + part2[2][t] + part2[3][t];
        Zpart[(size_t)b * 2048 + qt * 256 + kt * 32 + t] = z;
    }
}

// ---------------------------------------------------------------------------
// Kernel 3: out[b][q][d] = sum_k P*c*v, c = 1/sum Zpart (verbatim R9).
// grid 512 blocks, 256 threads; waves split k, LDS tree-combine.
// ---------------------------------------------------------------------------
__global__ __launch_bounds__(256) void pv_kernel(
    const float* __restrict__ P, const float* __restrict__ Zpart,
    const float* __restrict__ values, float* __restrict__ out)
{
    __shared__ float ps[4 * 260];
    __shared__ float red[4 * 512];
    const int b  = blockIdx.x >> 6;
    const int q0 = (blockIdx.x & 63) * 4;
    const int t  = threadIdx.x;

    {
        const int q = t >> 6;
        const int k = (t & 63) * 4;
        const float* zb = Zpart + (size_t)b * 2048 + k;
        float4 z = make_float4(0.f, 0.f, 0.f, 0.f);
        #pragma unroll
        for (int qt = 0; qt < 8; ++qt) {
            float4 a = *(const float4*)(zb + qt * 256);
            z.x += a.x; z.y += a.y; z.z += a.z; z.w += a.w;
        }
        const float* prow = P + ((size_t)(b * 256 + q0 + q)) * 256 + k;
        float4 s = *(const float4*)prow;
        float4 r;
        r.x = s.x * __builtin_amdgcn_rcpf(z.x);
        r.y = s.y * __builtin_amdgcn_rcpf(z.y);
        r.z = s.z * __builtin_amdgcn_rcpf(z.z);
        r.w = s.w * __builtin_amdgcn_rcpf(z.w);
        *(float4*)&ps[q * 260 + k] = r;
    }
    __syncthreads();

    const int wid  = t >> 6;
    const int lane = t & 63;
    const float* vb = values + (size_t)b * 256 * 128 + lane * 2;

    float ax[4] = {0.f, 0.f, 0.f, 0.f};
    float ay[4] = {0.f, 0.f, 0.f, 0.f};

    for (int kk4 = wid * 16; kk4 < wid * 16 + 16; ++kk4) {
        float4 p0 = *(const float4*)&ps[0 * 260 + kk4 * 4];
        float4 p1 = *(const float4*)&ps[1 * 260 + kk4 * 4];
        float4 p2 = *(const float4*)&ps[2 * 260 + kk4 * 4];
        float4 p3 = *(const float4*)&ps[3 * 260 + kk4 * 4];
        #pragma unroll
        for (int u = 0; u < 4; ++u) {
            int kk = kk4 * 4 + u;
            float2 v = *(const float2*)(vb + (size_t)kk * 128);
            float f0 = (&p0.x)[u], f1 = (&p1.x)[u], f2 = (&p2.x)[u], f3 = (&p3.x)[u];
            ax[0] = fmaf(f0, v.x, ax[0]); ay[0] = fmaf(f0, v.y, ay[0]);
            ax[1] = fmaf(f1, v.x, ax[1]); ay[1] = fmaf(f1, v.y, ay[1]);
            ax[2] = fmaf(f2, v.x, ax[2]); ay[2] = fmaf(f2, v.y, ay[2]);
            ax[3] = fmaf(f3, v.x, ax[3]); ay[3] = fmaf(f3, v.y, ay[3]);
        }
    }

    #pragma unroll
    for (int q = 0; q < 4; ++q)
        *(float2*)&red[wid * 512 + q * 128 + lane * 2] = make_float2(ax[q], ay[q]);
    __syncthreads();

    {
        const int j = t * 2;
        float2 s = make_float2(0.f, 0.f);
        #pragma unroll
        for (int w = 0; w < 4; ++w) {
            float2 r = *(const float2*)&red[w * 512 + j];
            s.x += r.x; s.y += r.y;
        }
        const int q = j >> 7, d = j & 127;
        *(float2*)&out[((size_t)(b * 256 + q0 + q)) * 128 + d] = s;
    }
}

// ---------------------------------------------------------------------------
extern "C" void kernel_launch(void* const* d_in, const int* in_sizes, int n_in,
                              void* d_out, int out_size, void* d_ws, size_t ws_size,
                              hipStream_t stream)
{
    const float* queries = (const float*)d_in[0];  // (8,256,128)
    const float* keys    = (const float*)d_in[1];  // (8,256,128)
    const float* values  = (const float*)d_in[2];  // (8,256,128)
    const float* Wq      = (const float*)d_in[3];  // (128,128)
    const float* Wk      = (const float*)d_in[4];  // (128,128)
    const float* wv      = (const float*)d_in[5];  // (128,)
    float* out = (float*)d_out;                    // (8,256,128)

    float* ws = (float*)d_ws;
    float* eqb   = ws;                   // 262144 floats  e^{2*qproj}
    float* ekb   = ws + 262144;          // 262144 floats  e^{2*kproj}
    float* P     = ws + 524288;          // 524288 floats  exp(score)
    float* Zpart = ws + 1048576;         // 16384 floats
    float* WqT   = ws + 1064960;         // 16384 floats
    float* WkT   = ws + 1081344;         // 16384 floats

    transposeW_kernel<<<32, 256, 0, stream>>>(Wq, Wk, WqT, WkT);
    proj_kernel<<<512, 256, 0, stream>>>(queries, keys, WqT, WkT, eqb, ekb);
    scoreP_kernel<<<dim3(8, 8, 8), 256, 0, stream>>>(eqb, ekb, wv, P, Zpart);
    pv_kernel<<<512, 256, 0, stream>>>(P, Zpart, values, out);
}